// Round 7
// baseline (390.192 us; speedup 1.0000x reference)
//
#include <hip/hip_runtime.h>

// ---------------------------------------------------------------------------
// VoxMLP round 13: round-11 revert (best: voxmlp 166us) + two latency fixes.
//   Round 12 (K=128 MX) regressed: matrix pipe wasn't critical; added 1.7M
//   LDS bank conflicts + 25MB scratch. Reverted to K=32 paired-fp8 MLP.
//   New:
//   (1) phase-1 wave-parallelization: all 64 lanes do trilinear (half-split
//       over x-corner, combine via __shfl_xor(.,32)) then pos-enc (32 slots
//       per lane-half). Old role-split executed BOTH paths serially at full
//       wave cost; this halves phase-1 issue count.
//   (2) prep dgrid: 2 independent voxel chunks per thread (4096 blocks).
//       prep sits ~4x off its memory roofline -> latency-bound hypothesis;
//       doubling memory-level parallelism tests and (if right) fixes it.
//   Kept: pt-inner MLP, SCHED_FENCE hoisting bounds, (256,5), streamed
//   pos-enc, vsin epilogue, byte-offset trilinear addressing.
// ---------------------------------------------------------------------------

typedef __attribute__((ext_vector_type(4))) float f4;
typedef long long llg;                                    // 8 x fp8
typedef __attribute__((ext_vector_type(2))) long long llg2;  // 16 x fp8 (4 VGPR)

#define MFMA8 __builtin_amdgcn_mfma_f32_16x16x32_fp8_fp8
#define SCHED_FENCE() __builtin_amdgcn_sched_barrier(0)

__device__ __forceinline__ float bf2f(unsigned int u) {
    union { float f; unsigned int i; } v; v.i = u << 16; return v.f;
}
__device__ __forceinline__ unsigned int pkbf(float a, float b) {
    unsigned int r;
    asm("v_cvt_pk_bf16_f32 %0, %1, %2" : "=v"(r) : "v"(a), "v"(b));
    return r;
}
__device__ __forceinline__ float vfract(float a) {
    float d; asm("v_fract_f32 %0, %1" : "=v"(d) : "v"(a)); return d;
}
__device__ __forceinline__ float vsin(float a) {
    float d; asm("v_sin_f32 %0, %1" : "=v"(d) : "v"(a)); return d;
}
__device__ __forceinline__ float gv(const float* __restrict__ g, int i, int j, int k) {
    return g[(i * 256 + j) * 256 + k];
}
// feature permutation: slot k' -> original feature index (or -1 = zero pad)
__device__ __forceinline__ int featmap(int kp) {
    if (kp < 3) return kp;
    if (kp == 3) return -1;
    const int m = kp - 4, b = m / 6, r = m - 6 * b, d = r >> 1, c = r & 1;
    return 3 + 6 * b + 3 * c + d;
}
// hidden-layer K permutation: storage slot k -> producing-layer unit index,
// chosen so the producer's packed C dwords are directly the B-fragment.
__device__ __forceinline__ int hidperm(int k) {
    const int kt = k >> 5, q = (k >> 3) & 3, j = k & 7;
    return 32 * kt + ((j >> 2) << 4) + (q << 2) + (j & 3);
}
__device__ __forceinline__ llg mkllg(unsigned int lo, unsigned int hi) {
    return (llg)(((unsigned long long)lo) | (((unsigned long long)hi) << 32));
}
__device__ __forceinline__ unsigned int pack8(f4 acc) {
    int d = __builtin_amdgcn_cvt_pk_fp8_f32(fmaxf(acc[0], 0.f), fmaxf(acc[1], 0.f), 0, false);
    d     = __builtin_amdgcn_cvt_pk_fp8_f32(fmaxf(acc[2], 0.f), fmaxf(acc[3], 0.f), d, true);
    return (unsigned int)d;
}

// ---- d_ws layout ----
// bytes [0, 67584): fp8 weight fragments, PAIRED layout:
//   byte = region + ((nt*KTP + ktp)*64 + lane)*16 + half*8 + j,  kt = 2*ktp+half
//   L0@0 (K64, KTP=1), L1@8192 (K128, KTP=2), L2@24576, L3@40960 (K192, KTP=3),
//   out@65536 (K128, KTP=2, NT=1, wo*2^13)
// shorts from 131072 (byte 262144): bf16x4 data grid (16.7M voxels * 8 B)
#define WS_TOTAL 67584
#define SWZ_BLOCKS 264          // 264*256 == 67584 (one byte per thread)
#define DG_BLOCKS 4096          // 2^20 threads x 2 chunks x 8 voxels
#define DG_OFF_SH 131072
#define WS_NEED (262144ull + 16777216ull * 8ull)
#define WO_SCALE 8192.0f
#define WO_INV   (1.0f / 8192.0f)
#define INV2PI 0.15915494309189535f

// Build 8 voxels of the bf16x4 [v,gx,gy,gz] data grid for chunk index t.
__device__ __forceinline__ void dg_one(const float* __restrict__ g,
                                       unsigned short* __restrict__ dg, int t)
{
    const int k0 = (t & 31) << 3;
    const int j  = (t >> 5) & 255;
    const int i  = t >> 13;
    const float* row = g + (i * 256 + j) * 256;
    const float* rxp = g + (min(i + 1, 255) * 256 + j) * 256;
    const float* rxm = g + (max(i - 1, 0)   * 256 + j) * 256;
    const float* ryp = g + (i * 256 + min(j + 1, 255)) * 256;
    const float* rym = g + (i * 256 + max(j - 1, 0))   * 256;
    float se[8], sxp[8], sxm[8], syp[8], sym[8];
    {
        f4 a = *(const f4*)(row + k0), b = *(const f4*)(row + k0 + 4);
        #pragma unroll
        for (int q = 0; q < 4; ++q) { se[q] = a[q]; se[q + 4] = b[q]; }
        a = *(const f4*)(rxp + k0); b = *(const f4*)(rxp + k0 + 4);
        #pragma unroll
        for (int q = 0; q < 4; ++q) { sxp[q] = a[q]; sxp[q + 4] = b[q]; }
        a = *(const f4*)(rxm + k0); b = *(const f4*)(rxm + k0 + 4);
        #pragma unroll
        for (int q = 0; q < 4; ++q) { sxm[q] = a[q]; sxm[q + 4] = b[q]; }
        a = *(const f4*)(ryp + k0); b = *(const f4*)(ryp + k0 + 4);
        #pragma unroll
        for (int q = 0; q < 4; ++q) { syp[q] = a[q]; syp[q + 4] = b[q]; }
        a = *(const f4*)(rym + k0); b = *(const f4*)(rym + k0 + 4);
        #pragma unroll
        for (int q = 0; q < 4; ++q) { sym[q] = a[q]; sym[q + 4] = b[q]; }
    }
    float zv[10];
    zv[0] = row[max(k0 - 1, 0)];
    #pragma unroll
    for (int q = 0; q < 8; ++q) zv[q + 1] = se[q];
    zv[9] = row[min(k0 + 8, 255)];
    unsigned int o[16];
    #pragma unroll
    for (int q = 0; q < 8; ++q) {
        o[q * 2 + 0] = pkbf(se[q], (sxp[q] - sxm[q]) * 63.75f);
        o[q * 2 + 1] = pkbf((syp[q] - sym[q]) * 63.75f, (zv[q + 2] - zv[q]) * 63.75f);
    }
    unsigned short* dst = dg + (size_t)(((i * 256 + j) * 256 + k0)) * 4;
    #pragma unroll
    for (int q = 0; q < 4; ++q)
        *(uint4*)(dst + q * 8) = *(const uint4*)(&o[q * 4]);
}

__global__ __launch_bounds__(256) void prep(
    const float* __restrict__ g,
    const float* __restrict__ w0, const float* __restrict__ w1,
    const float* __restrict__ w2, const float* __restrict__ w3,
    const float* __restrict__ wo,
    unsigned char* __restrict__ ws8, unsigned short* __restrict__ dg,
    int do_dgrid)
{
    const int bid = blockIdx.x;
    if (bid < SWZ_BLOCKS) {
        // ---------------- weight swizzle -> fp8 (paired layout) -----------
        int idx = bid * 256 + threadIdx.x;
        const float* src; int base, KTP, Kact, Nact, ld;
        if (idx < 8192)       { src = w0; base = 0;     KTP = 1; Kact = 64;  Nact = 128; ld = 128; }
        else if (idx < 24576) { src = w1; base = 8192;  KTP = 2; Kact = 128; Nact = 128; ld = 128; }
        else if (idx < 40960) { src = w2; base = 24576; KTP = 2; Kact = 128; Nact = 128; ld = 128; }
        else if (idx < 65536) { src = w3; base = 40960; KTP = 3; Kact = 192; Nact = 128; ld = 128; }
        else                  { src = wo; base = 65536; KTP = 2; Kact = 128; Nact = 3;   ld = 3;   }
        int local = idx - base;
        int j    = local & 7;
        int half = (local >> 3) & 1;
        int lane = (local >> 4) & 63;
        int c    = local >> 10;
        int ktp  = c % KTP, nt = c / KTP;
        int kt   = ktp * 2 + half;
        int k = kt * 32 + ((lane >> 4) << 3) + j;   // k = kt*32 + quad*8 + j
        int n = nt * 16 + (lane & 15);              // unit = nt*16 + (lane&15)
        float v = 0.0f;
        if (k < Kact && n < Nact) {
            int ko;
            if (base == 0) {
                ko = featmap(k);                     // L0: features
            } else if (base == 40960) {
                if (k >= 128) {                      // L3 tail: features
                    int f = featmap(k - 128);
                    ko = (f < 0) ? -1 : 128 + f;
                } else {
                    ko = hidperm(k);                 // L3 head: L2 units
                }
            } else {
                ko = hidperm(k);                     // L1/L2/out: hidden units
            }
            if (ko >= 0) v = src[ko * ld + n];
            if (base == 65536) v *= WO_SCALE;        // keep wo out of fp8 underflow
        }
        int p = __builtin_amdgcn_cvt_pk_fp8_f32(v, v, 0, false);
        ws8[idx] = (unsigned char)(p & 0xff);
    } else if (do_dgrid) {
        // -------- data grid build: 2 independent chunks per thread --------
        const int t0 = (bid - SWZ_BLOCKS) * 256 + threadIdx.x;   // [0, 2^20)
        dg_one(g, dg, t0);
        dg_one(g, dg, t0 + DG_BLOCKS * 256);
    }
}

// per-wave LDS (bytes): fbuf 32 rows x 88 B:
//   [0..63] fp8 features, [64..75] 3 fp32 c1..c3 stash.
#define FSTRIDE_B 88
#define WV_BYTES (32 * FSTRIDE_B)    // 2816

// Hidden layer (K=128): SRCP/DSTP are llg[2][4] pair arrays, pt-inner.
// SCHED_FENCE at each utp boundary bounds weight-fragment hoisting.
#define HIDDEN_LAYER(WSL, BIASP, SRCP, DSTP)                                    \
    do {                                                                        \
        _Pragma("unroll")                                                       \
        for (int utp = 0; utp < 4; ++utp) {                                     \
            const int utA = 2 * utp, utB = 2 * utp + 1;                         \
            llg2 wa0 = *(const llg2*)((WSL) + ((utA * 2 + 0) * 64 + lane) * 16);\
            llg2 wa1 = *(const llg2*)((WSL) + ((utA * 2 + 1) * 64 + lane) * 16);\
            llg2 wb0 = *(const llg2*)((WSL) + ((utB * 2 + 0) * 64 + lane) * 16);\
            llg2 wb1 = *(const llg2*)((WSL) + ((utB * 2 + 1) * 64 + lane) * 16);\
            const f4 biasA = *(const f4*)((BIASP) + utA * 16 + quad * 4);       \
            const f4 biasB = *(const f4*)((BIASP) + utB * 16 + quad * 4);       \
            _Pragma("unroll")                                                   \
            for (int pt = 0; pt < 2; ++pt) {                                    \
                f4 a0 = biasA, a1 = biasB;                                      \
                a0 = MFMA8(wa0[0], SRCP[pt][0], a0, 0, 0, 0);                   \
                a0 = MFMA8(wa0[1], SRCP[pt][1], a0, 0, 0, 0);                   \
                a0 = MFMA8(wa1[0], SRCP[pt][2], a0, 0, 0, 0);                   \
                a0 = MFMA8(wa1[1], SRCP[pt][3], a0, 0, 0, 0);                   \
                a1 = MFMA8(wb0[0], SRCP[pt][0], a1, 0, 0, 0);                   \
                a1 = MFMA8(wb0[1], SRCP[pt][1], a1, 0, 0, 0);                   \
                a1 = MFMA8(wb1[0], SRCP[pt][2], a1, 0, 0, 0);                   \
                a1 = MFMA8(wb1[1], SRCP[pt][3], a1, 0, 0, 0);                   \
                DSTP[pt][utp] = mkllg(pack8(a0), pack8(a1));                    \
            }                                                                   \
            SCHED_FENCE();                                                      \
        }                                                                       \
    } while (0)

template<bool FAST>
__global__ __launch_bounds__(256, 5) void voxmlp(
    const float* __restrict__ x, const float* __restrict__ grid,
    const unsigned char* __restrict__ ws8, const unsigned short* __restrict__ dg,
    const float* __restrict__ b0, const float* __restrict__ b1,
    const float* __restrict__ b2, const float* __restrict__ b3,
    const float* __restrict__ bo,
    float* __restrict__ out, int B)
{
    __shared__ unsigned char smem[WV_BYTES * 4];   // 11264 B

    const int lane = threadIdx.x & 63;
    const int wave = threadIdx.x >> 6;
    const int quad = lane >> 4;
    const int lm   = lane & 15;
    unsigned char* fbuf = smem + wave * WV_BYTES;

    const int pbase = blockIdx.x * 128 + wave * 32;

    // ================= Phase 1 (all 64 lanes on both tasks) ===============
    const int p2   = lane & 31;
    const int half = lane >> 5;
    const int pid  = pbase + p2;

    const float px = x[pid * 3 + 0];
    const float py = x[pid * 3 + 1];
    const float pz = x[pid * 3 + 2];

    // ---- trilinear: lane half handles x-corner `half`, 4 corners each ----
    {
        const float fx = (px + 1.0f) * 127.5f;
        const float fy = (py + 1.0f) * 127.5f;
        const float fz = (pz + 1.0f) * 127.5f;
        const float fx0 = floorf(fx), fy0 = floorf(fy), fz0 = floorf(fz);
        const float xd = fx - fx0, yd = fy - fy0, zd = fz - fz0;
        const int ix0 = min(max((int)fx0, 0), 255);
        const int iy0 = min(max((int)fy0, 0), 255);
        const int iz0 = min(max((int)fz0, 0), 255);
        const int ix1 = min(ix0 + 1, 255);
        const int iy1 = min(iy0 + 1, 255);
        const int iz1 = min(iz0 + 1, 255);
        const float wx = half ? xd : 1.0f - xd;

        float ret0 = 0.f, c1 = 0.f, c2 = 0.f, c3 = 0.f;
        if (FAST) {
            const unsigned char* dgb = (const unsigned char*)dg;
            const unsigned int vb = (unsigned int)((ix0 * 65536 + iy0 * 256 + iz0) << 3)
                                  + (half ? (unsigned int)((ix1 - ix0) << 19) : 0u);
            const unsigned int oy = (unsigned int)((iy1 - iy0) << 11);
            const unsigned int oz = (unsigned int)((iz1 - iz0) << 3);
            #pragma unroll
            for (int c = 0; c < 4; ++c) {
                const float wgt = wx * ((c & 2) ? yd : 1.0f - yd) *
                                       ((c & 1) ? zd : 1.0f - zd);
                const unsigned int off = vb + ((c & 2) ? oy : 0u)
                                            + ((c & 1) ? oz : 0u);
                const uint2 w = *(const uint2*)(dgb + off);
                ret0 = fmaf(wgt, bf2f(w.x & 0xffffu), ret0);
                c1   = fmaf(wgt, bf2f(w.x >> 16),     c1);
                c2   = fmaf(wgt, bf2f(w.y & 0xffffu), c2);
                c3   = fmaf(wgt, bf2f(w.y >> 16),     c3);
            }
        } else {
            const int i = half ? ix1 : ix0;
            #pragma unroll
            for (int c = 0; c < 4; ++c) {
                const int j = (c & 2) ? iy1 : iy0;
                const int k = (c & 1) ? iz1 : iz0;
                const float wgt = wx * ((c & 2) ? yd : 1.0f - yd) *
                                       ((c & 1) ? zd : 1.0f - zd);
                const float v  = gv(grid, i, j, k);
                const float gx = (gv(grid, min(i + 1, 255), j, k) - gv(grid, max(i - 1, 0), j, k)) * 63.75f;
                const float gy = (gv(grid, i, min(j + 1, 255), k) - gv(grid, i, max(j - 1, 0), k)) * 63.75f;
                const float gz = (gv(grid, i, j, min(k + 1, 255)) - gv(grid, i, j, max(k - 1, 0))) * 63.75f;
                ret0 = fmaf(wgt, v,  ret0);
                c1   = fmaf(wgt, gx, c1);
                c2   = fmaf(wgt, gy, c2);
                c3   = fmaf(wgt, gz, c3);
            }
        }
        // combine x-halves: lane l + lane l^32 hold complementary sums
        ret0 += __shfl_xor(ret0, 32);
        c1   += __shfl_xor(c1, 32);
        c2   += __shfl_xor(c2, 32);
        c3   += __shfl_xor(c3, 32);
        if (half == 0) {
            out[pid] = ret0;
            out[B + pid * 3 + 0] = c1;
            out[B + pid * 3 + 1] = c2;
            out[B + pid * 3 + 2] = c3;
            float* cst = (float*)(fbuf + p2 * FSTRIDE_B + 64);
            cst[0] = c1; cst[1] = c2; cst[2] = c3;
        }
    }

    // ---- streamed pos-enc: lane half handles slots [32*half, 32*half+32) --
    {
        const float r0 = px * INV2PI, r1 = py * INV2PI, r2 = pz * INV2PI;
        unsigned char* fb = fbuf + p2 * FSTRIDE_B;
        auto slotv = [&](int n) -> float {
            if (n == 0) return px;
            if (n == 1) return py;
            if (n == 2) return pz;
            if (n == 3) return 0.0f;
            const int m = n - 4, b = m / 6, t = m % 6, ax = t >> 1, ph = t & 1;
            const float rr = (ax == 0) ? r0 : (ax == 1) ? r1 : r2;
            const float arg = rr * (float)(1 << b) + (ph ? 0.25f : 0.0f);
            return vsin(vfract(arg));
        };
        #pragma unroll
        for (int w = 0; w < 4; ++w) {
            const int s0 = half * 32 + w * 8;
            int lo = __builtin_amdgcn_cvt_pk_fp8_f32(slotv(s0 + 0), slotv(s0 + 1), 0, false);
            lo     = __builtin_amdgcn_cvt_pk_fp8_f32(slotv(s0 + 2), slotv(s0 + 3), lo, true);
            int hi = __builtin_amdgcn_cvt_pk_fp8_f32(slotv(s0 + 4), slotv(s0 + 5), 0, false);
            hi     = __builtin_amdgcn_cvt_pk_fp8_f32(slotv(s0 + 6), slotv(s0 + 7), hi, true);
            uint2 pk; pk.x = (unsigned int)lo; pk.y = (unsigned int)hi;
            *(uint2*)(fb + (half * 4 + w) * 8) = pk;
        }
    }
    __builtin_amdgcn_s_barrier();   // phase-align waves (weight L1 reuse)

    // ================= MLP via fp8 MFMA, activations as llg pairs =========
    const int frow0 = lm * FSTRIDE_B + quad * 8;

    llg actA[2][4];   // L0 out, later L2 out
    llg actB[2][4];   // L1 out, later L3 out
    llg ffp[2][2];    // feature fragments (used by L0 and L3)

    #pragma unroll
    for (int pt = 0; pt < 2; ++pt)
        #pragma unroll
        for (int kt = 0; kt < 2; ++kt)
            ffp[pt][kt] = *(const llg*)(fbuf + pt * 16 * FSTRIDE_B + frow0 + kt * 32);

    // ---- L0: features (K=64, KTP=1) -> actA ----
    #pragma unroll
    for (int utp = 0; utp < 4; ++utp) {
        const int utA = 2 * utp, utB = 2 * utp + 1;
        llg2 wA = *(const llg2*)(ws8 + (utA * 64 + lane) * 16);
        llg2 wB = *(const llg2*)(ws8 + (utB * 64 + lane) * 16);
        const f4 biasA = *(const f4*)(b0 + utA * 16 + quad * 4);
        const f4 biasB = *(const f4*)(b0 + utB * 16 + quad * 4);
        #pragma unroll
        for (int pt = 0; pt < 2; ++pt) {
            f4 a0 = biasA, a1 = biasB;
            a0 = MFMA8(wA[0], ffp[pt][0], a0, 0, 0, 0);
            a0 = MFMA8(wA[1], ffp[pt][1], a0, 0, 0, 0);
            a1 = MFMA8(wB[0], ffp[pt][0], a1, 0, 0, 0);
            a1 = MFMA8(wB[1], ffp[pt][1], a1, 0, 0, 0);
            actA[pt][utp] = mkllg(pack8(a0), pack8(a1));
        }
        SCHED_FENCE();
    }

    // ---- L1, L2 (K=128, KTP=2) ----
    HIDDEN_LAYER(ws8 + 8192,  b1, actA, actB);
    HIDDEN_LAYER(ws8 + 24576, b2, actB, actA);

    // ---- L3: concat(actA K=128, features K=64) -> actB  (KTP=3) ----
    #pragma unroll
    for (int utp = 0; utp < 4; ++utp) {
        const int utA = 2 * utp, utB = 2 * utp + 1;
        llg2 ha0 = *(const llg2*)(ws8 + 40960 + ((utA * 3 + 0) * 64 + lane) * 16);
        llg2 ha1 = *(const llg2*)(ws8 + 40960 + ((utA * 3 + 1) * 64 + lane) * 16);
        llg2 ha2 = *(const llg2*)(ws8 + 40960 + ((utA * 3 + 2) * 64 + lane) * 16);
        llg2 hb0 = *(const llg2*)(ws8 + 40960 + ((utB * 3 + 0) * 64 + lane) * 16);
        llg2 hb1 = *(const llg2*)(ws8 + 40960 + ((utB * 3 + 1) * 64 + lane) * 16);
        llg2 hb2 = *(const llg2*)(ws8 + 40960 + ((utB * 3 + 2) * 64 + lane) * 16);
        const f4 biasA = *(const f4*)(b3 + utA * 16 + quad * 4);
        const f4 biasB = *(const f4*)(b3 + utB * 16 + quad * 4);
        #pragma unroll
        for (int pt = 0; pt < 2; ++pt) {
            f4 a0 = biasA, a1 = biasB;
            a0 = MFMA8(ha0[0], actA[pt][0], a0, 0, 0, 0);
            a0 = MFMA8(ha0[1], actA[pt][1], a0, 0, 0, 0);
            a0 = MFMA8(ha1[0], actA[pt][2], a0, 0, 0, 0);
            a0 = MFMA8(ha1[1], actA[pt][3], a0, 0, 0, 0);
            a0 = MFMA8(ha2[0], ffp[pt][0],  a0, 0, 0, 0);
            a0 = MFMA8(ha2[1], ffp[pt][1],  a0, 0, 0, 0);
            a1 = MFMA8(hb0[0], actA[pt][0], a1, 0, 0, 0);
            a1 = MFMA8(hb0[1], actA[pt][1], a1, 0, 0, 0);
            a1 = MFMA8(hb1[0], actA[pt][2], a1, 0, 0, 0);
            a1 = MFMA8(hb1[1], actA[pt][3], a1, 0, 0, 0);
            a1 = MFMA8(hb2[0], ffp[pt][0],  a1, 0, 0, 0);
            a1 = MFMA8(hb2[1], ffp[pt][1],  a1, 0, 0, 0);
            actB[pt][utp] = mkllg(pack8(a0), pack8(a1));
        }
        SCHED_FENCE();
    }

    // ---- output layer (K=128, KTP=2, N=3, wo scaled 2^13) + epilogue ----
    const llg2 o0 = *(const llg2*)(ws8 + 65536 + (lane * 16));
    const llg2 o1 = *(const llg2*)(ws8 + 65536 + ((64 + lane) * 16));

    const float bo0 = bo[0], bo1 = bo[1], bo2 = bo[2];
    #pragma unroll
    for (int pt = 0; pt < 2; ++pt) {
        f4 acc = {0.f, 0.f, 0.f, 0.f};
        acc = MFMA8(o0[0], actB[pt][0], acc, 0, 0, 0);
        acc = MFMA8(o0[1], actB[pt][1], acc, 0, 0, 0);
        acc = MFMA8(o1[0], actB[pt][2], acc, 0, 0, 0);
        acc = MFMA8(o1[1], actB[pt][3], acc, 0, 0, 0);

        const int pp = pt * 16 + lm;
        const float* cst = (const float*)(fbuf + pp * FSTRIDE_B + 64);
        const float g1 = cst[0], g2 = cst[1], g3 = cst[2];
        const float r0 = acc[0] * WO_INV + bo0;
        const float r1 = acc[1] * WO_INV + bo1;
        const float r2 = acc[2] * WO_INV + bo2;
        const float theta = sqrtf(fmaf(r0, r0, fmaf(r1, r1, r2 * r2)) + 1e-12f);
        const float it = __builtin_amdgcn_rcpf(theta);
        const float e0 = r0 * it, e1 = r1 * it, e2 = r2 * it;
        const float a = sqrtf(fmaf(g1, g1, fmaf(g2, g2, g3 * g3)) + 1e-12f);
        const float ia = __builtin_amdgcn_rcpf(a);
        const float v0 = g1 * ia, v1 = g2 * ia, v2 = g3 * ia;
        const float rv = theta * INV2PI;
        const float st = vsin(vfract(rv));
        const float ct = vsin(vfract(rv + 0.25f));
        const float cx = e1 * v2 - e2 * v1;
        const float cy = e2 * v0 - e0 * v2;
        const float cz = e0 * v1 - e1 * v0;
        const float om = (1.0f - ct) * (e0 * v0 + e1 * v1 + e2 * v2);
        if (quad == 0) {
            const int pid2 = pbase + pp;
            out[4 * B + pid2 * 3 + 0] = a * (ct * v0 + st * cx + om * e0);
            out[4 * B + pid2 * 3 + 1] = a * (ct * v1 + st * cy + om * e1);
            out[4 * B + pid2 * 3 + 2] = a * (ct * v2 + st * cz + om * e2);
        }
    }
}

extern "C" void kernel_launch(void* const* d_in, const int* in_sizes, int n_in,
                              void* d_out, int out_size, void* d_ws, size_t ws_size,
                              hipStream_t stream)
{
    const float* x    = (const float*)d_in[0];
    const float* grid = (const float*)d_in[1];
    const float* w0   = (const float*)d_in[2];
    const float* b0   = (const float*)d_in[3];
    const float* w1   = (const float*)d_in[4];
    const float* b1   = (const float*)d_in[5];
    const float* w2   = (const float*)d_in[6];
    const float* b2   = (const float*)d_in[7];
    const float* w3   = (const float*)d_in[8];
    const float* b3   = (const float*)d_in[9];
    const float* wo   = (const float*)d_in[10];
    const float* bo   = (const float*)d_in[11];
    float* out = (float*)d_out;
    unsigned char* ws8 = (unsigned char*)d_ws;
    unsigned short* dg = (unsigned short*)d_ws + DG_OFF_SH;

    const int B = in_sizes[0] / 3;        // 1,048,576
    const int fast = (ws_size >= WS_NEED) ? 1 : 0;
    const int nprep = fast ? (SWZ_BLOCKS + DG_BLOCKS) : SWZ_BLOCKS;
    prep<<<nprep, 256, 0, stream>>>(grid, w0, w1, w2, w3, wo, ws8, dg, fast);
    if (fast)
        voxmlp<true><<<B / 128, 256, 0, stream>>>(x, grid, ws8, dg, b0, b1, b2, b3, bo, out, B);
    else
        voxmlp<false><<<B / 128, 256, 0, stream>>>(x, grid, ws8, dg, b0, b1, b2, b3, bo, out, B);
}

// Round 8
// 337.878 us; speedup vs baseline: 1.1548x; 1.1548x over previous
//
#include <hip/hip_runtime.h>

// ---------------------------------------------------------------------------
// VoxMLP round 14: voxmlp = round-11 verbatim (166us, no spill).
//   Round 13 post-mortem: wave-parallel phase-1 respilled (+147MB writes;
//   VGPR_Count column does NOT show unified VGPR/AGPR pressure — WRITE_SIZE
//   is the sentinel). prep 2-chunk test: neutral -> not latency-bound.
//   One change this round, prep-side only: LDS-shared dgrid builder.
//   Block = (i, 32-wide k-slab) x all 256 j; center rows staged in LDS
//   (stride 36 floats: 16B-aligned, bank-balanced), y+-1 from LDS, only
//   x+-1 rows from global. Logical reads 640 -> 384 B per 32 voxels.
//   Bit-identical arithmetic (same pkbf, same clamps).
// ---------------------------------------------------------------------------

typedef __attribute__((ext_vector_type(4))) float f4;
typedef long long llg;                                    // 8 x fp8
typedef __attribute__((ext_vector_type(2))) long long llg2;  // 16 x fp8 (4 VGPR)

#define MFMA8 __builtin_amdgcn_mfma_f32_16x16x32_fp8_fp8
#define SCHED_FENCE() __builtin_amdgcn_sched_barrier(0)

__device__ __forceinline__ float bf2f(unsigned int u) {
    union { float f; unsigned int i; } v; v.i = u << 16; return v.f;
}
__device__ __forceinline__ unsigned int pkbf(float a, float b) {
    unsigned int r;
    asm("v_cvt_pk_bf16_f32 %0, %1, %2" : "=v"(r) : "v"(a), "v"(b));
    return r;
}
__device__ __forceinline__ float vfract(float a) {
    float d; asm("v_fract_f32 %0, %1" : "=v"(d) : "v"(a)); return d;
}
__device__ __forceinline__ float vsin(float a) {
    float d; asm("v_sin_f32 %0, %1" : "=v"(d) : "v"(a)); return d;
}
__device__ __forceinline__ float gv(const float* __restrict__ g, int i, int j, int k) {
    return g[(i * 256 + j) * 256 + k];
}
// feature permutation: slot k' -> original feature index (or -1 = zero pad)
__device__ __forceinline__ int featmap(int kp) {
    if (kp < 3) return kp;
    if (kp == 3) return -1;
    const int m = kp - 4, b = m / 6, r = m - 6 * b, d = r >> 1, c = r & 1;
    return 3 + 6 * b + 3 * c + d;
}
// hidden-layer K permutation: storage slot k -> producing-layer unit index,
// chosen so the producer's packed C dwords are directly the B-fragment.
__device__ __forceinline__ int hidperm(int k) {
    const int kt = k >> 5, q = (k >> 3) & 3, j = k & 7;
    return 32 * kt + ((j >> 2) << 4) + (q << 2) + (j & 3);
}
__device__ __forceinline__ llg mkllg(unsigned int lo, unsigned int hi) {
    return (llg)(((unsigned long long)lo) | (((unsigned long long)hi) << 32));
}
__device__ __forceinline__ unsigned int pack8(f4 acc) {
    int d = __builtin_amdgcn_cvt_pk_fp8_f32(fmaxf(acc[0], 0.f), fmaxf(acc[1], 0.f), 0, false);
    d     = __builtin_amdgcn_cvt_pk_fp8_f32(fmaxf(acc[2], 0.f), fmaxf(acc[3], 0.f), d, true);
    return (unsigned int)d;
}

// ---- d_ws layout ----
// bytes [0, 67584): fp8 weight fragments, PAIRED layout:
//   byte = region + ((nt*KTP + ktp)*64 + lane)*16 + half*8 + j,  kt = 2*ktp+half
//   L0@0 (K64, KTP=1), L1@8192 (K128, KTP=2), L2@24576, L3@40960 (K192, KTP=3),
//   out@65536 (K128, KTP=2, NT=1, wo*2^13)
// shorts from 131072 (byte 262144): bf16x4 data grid (16.7M voxels * 8 B)
#define WS_TOTAL 67584
#define SWZ_BLOCKS 264          // 264*256 == 67584 (one byte per thread)
#define DG_BLOCKS 2048          // 256 i x 8 k-slabs; 256 threads = j
#define DG_OFF_SH 131072
#define WS_NEED (262144ull + 16777216ull * 8ull)
#define WO_SCALE 8192.0f
#define WO_INV   (1.0f / 8192.0f)
#define INV2PI 0.15915494309189535f
#define LROW 36                 // LDS row stride (floats): 16B-aligned, balanced

__global__ __launch_bounds__(256) void prep(
    const float* __restrict__ g,
    const float* __restrict__ w0, const float* __restrict__ w1,
    const float* __restrict__ w2, const float* __restrict__ w3,
    const float* __restrict__ wo,
    unsigned char* __restrict__ ws8, unsigned short* __restrict__ dg,
    int do_dgrid)
{
    __shared__ float lds[256 * LROW];   // 36864 B (dgrid blocks only)
    const int bid = blockIdx.x;
    if (bid < SWZ_BLOCKS) {
        // ---------------- weight swizzle -> fp8 (paired layout) -----------
        int idx = bid * 256 + threadIdx.x;
        const float* src; int base, KTP, Kact, Nact, ld;
        if (idx < 8192)       { src = w0; base = 0;     KTP = 1; Kact = 64;  Nact = 128; ld = 128; }
        else if (idx < 24576) { src = w1; base = 8192;  KTP = 2; Kact = 128; Nact = 128; ld = 128; }
        else if (idx < 40960) { src = w2; base = 24576; KTP = 2; Kact = 128; Nact = 128; ld = 128; }
        else if (idx < 65536) { src = w3; base = 40960; KTP = 3; Kact = 192; Nact = 128; ld = 128; }
        else                  { src = wo; base = 65536; KTP = 2; Kact = 128; Nact = 3;   ld = 3;   }
        int local = idx - base;
        int j    = local & 7;
        int half = (local >> 3) & 1;
        int lane = (local >> 4) & 63;
        int c    = local >> 10;
        int ktp  = c % KTP, nt = c / KTP;
        int kt   = ktp * 2 + half;
        int k = kt * 32 + ((lane >> 4) << 3) + j;   // k = kt*32 + quad*8 + j
        int n = nt * 16 + (lane & 15);              // unit = nt*16 + (lane&15)
        float v = 0.0f;
        if (k < Kact && n < Nact) {
            int ko;
            if (base == 0) {
                ko = featmap(k);                     // L0: features
            } else if (base == 40960) {
                if (k >= 128) {                      // L3 tail: features
                    int f = featmap(k - 128);
                    ko = (f < 0) ? -1 : 128 + f;
                } else {
                    ko = hidperm(k);                 // L3 head: L2 units
                }
            } else {
                ko = hidperm(k);                     // L1/L2/out: hidden units
            }
            if (ko >= 0) v = src[ko * ld + n];
            if (base == 65536) v *= WO_SCALE;        // keep wo out of fp8 underflow
        }
        int p = __builtin_amdgcn_cvt_pk_fp8_f32(v, v, 0, false);
        ws8[idx] = (unsigned char)(p & 0xff);
    } else if (do_dgrid) {
        // -------- LDS-shared data grid build: block = (i, k-slab) ---------
        const int rb = bid - SWZ_BLOCKS;            // [0, 2048)
        const int i  = rb >> 3;
        const int k0 = (rb & 7) << 5;               // 0,32,...,224
        const int j  = threadIdx.x;                 // 0..255
        const float* row = g + (i * 256 + j) * 256 + k0;
        const float* rxp = g + (min(i + 1, 255) * 256 + j) * 256 + k0;
        const float* rxm = g + (max(i - 1, 0)   * 256 + j) * 256 + k0;
        float* myrow = lds + j * LROW;

        // center row chunk -> LDS; z halo scalars
        #pragma unroll
        for (int s = 0; s < 8; ++s)
            *(f4*)(myrow + s * 4) = *(const f4*)(row + s * 4);
        const float zlo = (k0 == 0)   ? row[0]  : row[-1];
        const float zhi = (k0 == 224) ? row[31] : row[32];
        __syncthreads();

        const float* ypr = lds + min(j + 1, 255) * LROW;
        const float* ymr = lds + max(j - 1, 0)   * LROW;
        unsigned short* dst = dg + (size_t)((i * 256 + j) * 256 + k0) * 4;

        #pragma unroll
        for (int s = 0; s < 4; ++s) {               // 8 voxels per subchunk
            const f4 xp0 = *(const f4*)(rxp + s * 8);
            const f4 xp1 = *(const f4*)(rxp + s * 8 + 4);
            const f4 xm0 = *(const f4*)(rxm + s * 8);
            const f4 xm1 = *(const f4*)(rxm + s * 8 + 4);
            const f4 yp0 = *(const f4*)(ypr + s * 8);
            const f4 yp1 = *(const f4*)(ypr + s * 8 + 4);
            const f4 ym0 = *(const f4*)(ymr + s * 8);
            const f4 ym1 = *(const f4*)(ymr + s * 8 + 4);
            const f4 c0  = *(const f4*)(myrow + s * 8);
            const f4 c1  = *(const f4*)(myrow + s * 8 + 4);
            const float zm = (s == 0) ? zlo : myrow[s * 8 - 1];
            const float zp = (s == 3) ? zhi : myrow[s * 8 + 8];

            float cen[8], xpv[8], xmv[8], ypv[8], ymv[8];
            #pragma unroll
            for (int q = 0; q < 4; ++q) {
                cen[q] = c0[q];  cen[q + 4] = c1[q];
                xpv[q] = xp0[q]; xpv[q + 4] = xp1[q];
                xmv[q] = xm0[q]; xmv[q + 4] = xm1[q];
                ypv[q] = yp0[q]; ypv[q + 4] = yp1[q];
                ymv[q] = ym0[q]; ymv[q + 4] = ym1[q];
            }
            float z[10];
            z[0] = zm;
            #pragma unroll
            for (int q = 0; q < 8; ++q) z[q + 1] = cen[q];
            z[9] = zp;

            unsigned int o[16];
            #pragma unroll
            for (int q = 0; q < 8; ++q) {
                o[q * 2 + 0] = pkbf(cen[q], (xpv[q] - xmv[q]) * 63.75f);
                o[q * 2 + 1] = pkbf((ypv[q] - ymv[q]) * 63.75f, (z[q + 2] - z[q]) * 63.75f);
            }
            #pragma unroll
            for (int q = 0; q < 4; ++q)
                *(uint4*)(dst + s * 32 + q * 8) = *(const uint4*)(&o[q * 4]);
        }
    }
}

// per-wave LDS (bytes): fbuf 32 rows x 88 B:
//   [0..63] fp8 features, [64..75] 3 fp32 c1..c3 stash.
#define FSTRIDE_B 88
#define WV_BYTES (32 * FSTRIDE_B)    // 2816

// Hidden layer (K=128): SRCP/DSTP are llg[2][4] pair arrays, pt-inner.
// SCHED_FENCE at each utp boundary bounds weight-fragment hoisting.
#define HIDDEN_LAYER(WSL, BIASP, SRCP, DSTP)                                    \
    do {                                                                        \
        _Pragma("unroll")                                                       \
        for (int utp = 0; utp < 4; ++utp) {                                     \
            const int utA = 2 * utp, utB = 2 * utp + 1;                         \
            llg2 wa0 = *(const llg2*)((WSL) + ((utA * 2 + 0) * 64 + lane) * 16);\
            llg2 wa1 = *(const llg2*)((WSL) + ((utA * 2 + 1) * 64 + lane) * 16);\
            llg2 wb0 = *(const llg2*)((WSL) + ((utB * 2 + 0) * 64 + lane) * 16);\
            llg2 wb1 = *(const llg2*)((WSL) + ((utB * 2 + 1) * 64 + lane) * 16);\
            const f4 biasA = *(const f4*)((BIASP) + utA * 16 + quad * 4);       \
            const f4 biasB = *(const f4*)((BIASP) + utB * 16 + quad * 4);       \
            _Pragma("unroll")                                                   \
            for (int pt = 0; pt < 2; ++pt) {                                    \
                f4 a0 = biasA, a1 = biasB;                                      \
                a0 = MFMA8(wa0[0], SRCP[pt][0], a0, 0, 0, 0);                   \
                a0 = MFMA8(wa0[1], SRCP[pt][1], a0, 0, 0, 0);                   \
                a0 = MFMA8(wa1[0], SRCP[pt][2], a0, 0, 0, 0);                   \
                a0 = MFMA8(wa1[1], SRCP[pt][3], a0, 0, 0, 0);                   \
                a1 = MFMA8(wb0[0], SRCP[pt][0], a1, 0, 0, 0);                   \
                a1 = MFMA8(wb0[1], SRCP[pt][1], a1, 0, 0, 0);                   \
                a1 = MFMA8(wb1[0], SRCP[pt][2], a1, 0, 0, 0);                   \
                a1 = MFMA8(wb1[1], SRCP[pt][3], a1, 0, 0, 0);                   \
                DSTP[pt][utp] = mkllg(pack8(a0), pack8(a1));                    \
            }                                                                   \
            SCHED_FENCE();                                                      \
        }                                                                       \
    } while (0)

template<bool FAST>
__global__ __launch_bounds__(256, 5) void voxmlp(
    const float* __restrict__ x, const float* __restrict__ grid,
    const unsigned char* __restrict__ ws8, const unsigned short* __restrict__ dg,
    const float* __restrict__ b0, const float* __restrict__ b1,
    const float* __restrict__ b2, const float* __restrict__ b3,
    const float* __restrict__ bo,
    float* __restrict__ out, int B)
{
    __shared__ unsigned char smem[WV_BYTES * 4];   // 11264 B

    const int lane = threadIdx.x & 63;
    const int wave = threadIdx.x >> 6;
    const int quad = lane >> 4;
    const int lm   = lane & 15;
    unsigned char* fbuf = smem + wave * WV_BYTES;

    const int pbase = blockIdx.x * 128 + wave * 32;

    // ================= Phase 1 ============================================
    const int p2   = lane & 31;
    const int role = lane >> 5;
    const int pid  = pbase + p2;

    const float px = x[pid * 3 + 0];
    const float py = x[pid * 3 + 1];
    const float pz = x[pid * 3 + 2];

    if (role == 0) {
        const float fx = (px + 1.0f) * 127.5f;
        const float fy = (py + 1.0f) * 127.5f;
        const float fz = (pz + 1.0f) * 127.5f;
        const float fx0 = floorf(fx), fy0 = floorf(fy), fz0 = floorf(fz);
        const float xd = fx - fx0, yd = fy - fy0, zd = fz - fz0;
        const int ix0 = min(max((int)fx0, 0), 255);
        const int iy0 = min(max((int)fy0, 0), 255);
        const int iz0 = min(max((int)fz0, 0), 255);
        const int ix1 = min(ix0 + 1, 255);
        const int iy1 = min(iy0 + 1, 255);
        const int iz1 = min(iz0 + 1, 255);

        float ret0 = 0.f, c1 = 0.f, c2 = 0.f, c3 = 0.f;
        if (FAST) {
            // byte-offset addressing: one 32-bit base + 3 axis deltas
            const unsigned char* dgb = (const unsigned char*)dg;
            const unsigned int vbase = (unsigned int)((ix0 * 65536 + iy0 * 256 + iz0) << 3);
            const unsigned int ox = (unsigned int)((ix1 - ix0) << 19);
            const unsigned int oy = (unsigned int)((iy1 - iy0) << 11);
            const unsigned int oz = (unsigned int)((iz1 - iz0) << 3);
            #pragma unroll
            for (int c = 0; c < 8; ++c) {
                const float wgt = ((c & 4) ? xd : 1.0f - xd) *
                                  ((c & 2) ? yd : 1.0f - yd) *
                                  ((c & 1) ? zd : 1.0f - zd);
                const unsigned int off = vbase + ((c & 4) ? ox : 0u)
                                               + ((c & 2) ? oy : 0u)
                                               + ((c & 1) ? oz : 0u);
                const uint2 w = *(const uint2*)(dgb + off);
                ret0 = fmaf(wgt, bf2f(w.x & 0xffffu), ret0);
                c1   = fmaf(wgt, bf2f(w.x >> 16),     c1);
                c2   = fmaf(wgt, bf2f(w.y & 0xffffu), c2);
                c3   = fmaf(wgt, bf2f(w.y >> 16),     c3);
            }
        } else {
            #pragma unroll
            for (int c = 0; c < 8; ++c) {
                const int i = (c & 4) ? ix1 : ix0;
                const int j = (c & 2) ? iy1 : iy0;
                const int k = (c & 1) ? iz1 : iz0;
                const float wgt = ((c & 4) ? xd : 1.0f - xd) *
                                  ((c & 2) ? yd : 1.0f - yd) *
                                  ((c & 1) ? zd : 1.0f - zd);
                const float v  = gv(grid, i, j, k);
                const float gx = (gv(grid, min(i + 1, 255), j, k) - gv(grid, max(i - 1, 0), j, k)) * 63.75f;
                const float gy = (gv(grid, i, min(j + 1, 255), k) - gv(grid, i, max(j - 1, 0), k)) * 63.75f;
                const float gz = (gv(grid, i, j, min(k + 1, 255)) - gv(grid, i, j, max(k - 1, 0))) * 63.75f;
                ret0 = fmaf(wgt, v,  ret0);
                c1   = fmaf(wgt, gx, c1);
                c2   = fmaf(wgt, gy, c2);
                c3   = fmaf(wgt, gz, c3);
            }
        }
        out[pid] = ret0;
        out[B + pid * 3 + 0] = c1;
        out[B + pid * 3 + 1] = c2;
        out[B + pid * 3 + 2] = c3;
        float* cst = (float*)(fbuf + p2 * FSTRIDE_B + 64);
        cst[0] = c1; cst[1] = c2; cst[2] = c3;
    } else {
        // streamed pos-enc: compute slot values in order, pack pairs into
        // dwords, ds_write each uint2 as soon as ready. Liveness ~8 floats.
        const float r0 = px * INV2PI, r1 = py * INV2PI, r2 = pz * INV2PI;
        unsigned char* fb = fbuf + p2 * FSTRIDE_B;
        auto slotv = [&](int n) -> float {
            if (n == 0) return px;
            if (n == 1) return py;
            if (n == 2) return pz;
            if (n == 3) return 0.0f;
            const int m = n - 4, b = m / 6, t = m % 6, ax = t >> 1, ph = t & 1;
            const float rr = (ax == 0) ? r0 : (ax == 1) ? r1 : r2;
            const float arg = rr * (float)(1 << b) + (ph ? 0.25f : 0.0f);
            return vsin(vfract(arg));
        };
        #pragma unroll
        for (int w = 0; w < 8; ++w) {
            int lo = __builtin_amdgcn_cvt_pk_fp8_f32(slotv(8 * w + 0), slotv(8 * w + 1), 0, false);
            lo     = __builtin_amdgcn_cvt_pk_fp8_f32(slotv(8 * w + 2), slotv(8 * w + 3), lo, true);
            int hi = __builtin_amdgcn_cvt_pk_fp8_f32(slotv(8 * w + 4), slotv(8 * w + 5), 0, false);
            hi     = __builtin_amdgcn_cvt_pk_fp8_f32(slotv(8 * w + 6), slotv(8 * w + 7), hi, true);
            uint2 pk; pk.x = (unsigned int)lo; pk.y = (unsigned int)hi;
            *(uint2*)(fb + w * 8) = pk;
        }
    }
    __builtin_amdgcn_s_barrier();   // phase-align waves (weight L1 reuse)

    // ================= MLP via fp8 MFMA, activations as llg pairs =========
    const int frow0 = lm * FSTRIDE_B + quad * 8;

    llg actA[2][4];   // L0 out, later L2 out
    llg actB[2][4];   // L1 out, later L3 out
    llg ffp[2][2];    // feature fragments (used by L0 and L3)

    #pragma unroll
    for (int pt = 0; pt < 2; ++pt)
        #pragma unroll
        for (int kt = 0; kt < 2; ++kt)
            ffp[pt][kt] = *(const llg*)(fbuf + pt * 16 * FSTRIDE_B + frow0 + kt * 32);

    // ---- L0: features (K=64, KTP=1) -> actA ----
    #pragma unroll
    for (int utp = 0; utp < 4; ++utp) {
        const int utA = 2 * utp, utB = 2 * utp + 1;
        llg2 wA = *(const llg2*)(ws8 + (utA * 64 + lane) * 16);
        llg2 wB = *(const llg2*)(ws8 + (utB * 64 + lane) * 16);
        const f4 biasA = *(const f4*)(b0 + utA * 16 + quad * 4);
        const f4 biasB = *(const f4*)(b0 + utB * 16 + quad * 4);
        #pragma unroll
        for (int pt = 0; pt < 2; ++pt) {
            f4 a0 = biasA, a1 = biasB;
            a0 = MFMA8(wA[0], ffp[pt][0], a0, 0, 0, 0);
            a0 = MFMA8(wA[1], ffp[pt][1], a0, 0, 0, 0);
            a1 = MFMA8(wB[0], ffp[pt][0], a1, 0, 0, 0);
            a1 = MFMA8(wB[1], ffp[pt][1], a1, 0, 0, 0);
            actA[pt][utp] = mkllg(pack8(a0), pack8(a1));
        }
        SCHED_FENCE();
    }

    // ---- L1, L2 (K=128, KTP=2) ----
    HIDDEN_LAYER(ws8 + 8192,  b1, actA, actB);
    HIDDEN_LAYER(ws8 + 24576, b2, actB, actA);

    // ---- L3: concat(actA K=128, features K=64) -> actB  (KTP=3) ----
    #pragma unroll
    for (int utp = 0; utp < 4; ++utp) {
        const int utA = 2 * utp, utB = 2 * utp + 1;
        llg2 ha0 = *(const llg2*)(ws8 + 40960 + ((utA * 3 + 0) * 64 + lane) * 16);
        llg2 ha1 = *(const llg2*)(ws8 + 40960 + ((utA * 3 + 1) * 64 + lane) * 16);
        llg2 ha2 = *(const llg2*)(ws8 + 40960 + ((utA * 3 + 2) * 64 + lane) * 16);
        llg2 hb0 = *(const llg2*)(ws8 + 40960 + ((utB * 3 + 0) * 64 + lane) * 16);
        llg2 hb1 = *(const llg2*)(ws8 + 40960 + ((utB * 3 + 1) * 64 + lane) * 16);
        llg2 hb2 = *(const llg2*)(ws8 + 40960 + ((utB * 3 + 2) * 64 + lane) * 16);
        const f4 biasA = *(const f4*)(b3 + utA * 16 + quad * 4);
        const f4 biasB = *(const f4*)(b3 + utB * 16 + quad * 4);
        #pragma unroll
        for (int pt = 0; pt < 2; ++pt) {
            f4 a0 = biasA, a1 = biasB;
            a0 = MFMA8(ha0[0], actA[pt][0], a0, 0, 0, 0);
            a0 = MFMA8(ha0[1], actA[pt][1], a0, 0, 0, 0);
            a0 = MFMA8(ha1[0], actA[pt][2], a0, 0, 0, 0);
            a0 = MFMA8(ha1[1], actA[pt][3], a0, 0, 0, 0);
            a0 = MFMA8(ha2[0], ffp[pt][0],  a0, 0, 0, 0);
            a0 = MFMA8(ha2[1], ffp[pt][1],  a0, 0, 0, 0);
            a1 = MFMA8(hb0[0], actA[pt][0], a1, 0, 0, 0);
            a1 = MFMA8(hb0[1], actA[pt][1], a1, 0, 0, 0);
            a1 = MFMA8(hb1[0], actA[pt][2], a1, 0, 0, 0);
            a1 = MFMA8(hb1[1], actA[pt][3], a1, 0, 0, 0);
            a1 = MFMA8(hb2[0], ffp[pt][0],  a1, 0, 0, 0);
            a1 = MFMA8(hb2[1], ffp[pt][1],  a1, 0, 0, 0);
            actB[pt][utp] = mkllg(pack8(a0), pack8(a1));
        }
        SCHED_FENCE();
    }

    // ---- output layer (K=128, KTP=2, N=3, wo scaled 2^13) + epilogue ----
    const llg2 o0 = *(const llg2*)(ws8 + 65536 + (lane * 16));
    const llg2 o1 = *(const llg2*)(ws8 + 65536 + ((64 + lane) * 16));

    const float bo0 = bo[0], bo1 = bo[1], bo2 = bo[2];
    #pragma unroll
    for (int pt = 0; pt < 2; ++pt) {
        f4 acc = {0.f, 0.f, 0.f, 0.f};
        acc = MFMA8(o0[0], actB[pt][0], acc, 0, 0, 0);
        acc = MFMA8(o0[1], actB[pt][1], acc, 0, 0, 0);
        acc = MFMA8(o1[0], actB[pt][2], acc, 0, 0, 0);
        acc = MFMA8(o1[1], actB[pt][3], acc, 0, 0, 0);

        const int pp = pt * 16 + lm;
        const float* cst = (const float*)(fbuf + pp * FSTRIDE_B + 64);
        const float g1 = cst[0], g2 = cst[1], g3 = cst[2];
        const float r0 = acc[0] * WO_INV + bo0;
        const float r1 = acc[1] * WO_INV + bo1;
        const float r2 = acc[2] * WO_INV + bo2;
        const float theta = sqrtf(fmaf(r0, r0, fmaf(r1, r1, r2 * r2)) + 1e-12f);
        const float it = __builtin_amdgcn_rcpf(theta);
        const float e0 = r0 * it, e1 = r1 * it, e2 = r2 * it;
        const float a = sqrtf(fmaf(g1, g1, fmaf(g2, g2, g3 * g3)) + 1e-12f);
        const float ia = __builtin_amdgcn_rcpf(a);
        const float v0 = g1 * ia, v1 = g2 * ia, v2 = g3 * ia;
        const float rv = theta * INV2PI;
        const float st = vsin(vfract(rv));
        const float ct = vsin(vfract(rv + 0.25f));
        const float cx = e1 * v2 - e2 * v1;
        const float cy = e2 * v0 - e0 * v2;
        const float cz = e0 * v1 - e1 * v0;
        const float om = (1.0f - ct) * (e0 * v0 + e1 * v1 + e2 * v2);
        if (quad == 0) {
            const int pid2 = pbase + pp;
            out[4 * B + pid2 * 3 + 0] = a * (ct * v0 + st * cx + om * e0);
            out[4 * B + pid2 * 3 + 1] = a * (ct * v1 + st * cy + om * e1);
            out[4 * B + pid2 * 3 + 2] = a * (ct * v2 + st * cz + om * e2);
        }
    }
}

extern "C" void kernel_launch(void* const* d_in, const int* in_sizes, int n_in,
                              void* d_out, int out_size, void* d_ws, size_t ws_size,
                              hipStream_t stream)
{
    const float* x    = (const float*)d_in[0];
    const float* grid = (const float*)d_in[1];
    const float* w0   = (const float*)d_in[2];
    const float* b0   = (const float*)d_in[3];
    const float* w1   = (const float*)d_in[4];
    const float* b1   = (const float*)d_in[5];
    const float* w2   = (const float*)d_in[6];
    const float* b2   = (const float*)d_in[7];
    const float* w3   = (const float*)d_in[8];
    const float* b3   = (const float*)d_in[9];
    const float* wo   = (const float*)d_in[10];
    const float* bo   = (const float*)d_in[11];
    float* out = (float*)d_out;
    unsigned char* ws8 = (unsigned char*)d_ws;
    unsigned short* dg = (unsigned short*)d_ws + DG_OFF_SH;

    const int B = in_sizes[0] / 3;        // 1,048,576
    const int fast = (ws_size >= WS_NEED) ? 1 : 0;
    const int nprep = fast ? (SWZ_BLOCKS + DG_BLOCKS) : SWZ_BLOCKS;
    prep<<<nprep, 256, 0, stream>>>(grid, w0, w1, w2, w3, wo, ws8, dg, fast);
    if (fast)
        voxmlp<true><<<B / 128, 256, 0, stream>>>(x, grid, ws8, dg, b0, b1, b2, b3, bo, out, B);
    else
        voxmlp<false><<<B / 128, 256, 0, stream>>>(x, grid, ws8, dg, b0, b1, b2, b3, bo, out, B);
}

// Round 9
// 316.454 us; speedup vs baseline: 1.2330x; 1.0677x over previous
//
#include <hip/hip_runtime.h>

// ---------------------------------------------------------------------------
// VoxMLP round 15: prep = round-11 streaming (LDS version regressed 155->170:
//   36KB shared reserved by every block halved occupancy; reverted).
//   voxmlp = round-11 + EARLY GATHER: the 8 dgrid corner loads are issued by
//   ALL 64 lanes before the role branch (role-1 lane l duplicates role-0
//   lane l-32's addresses -> same cache lines, no extra traffic), pinned via
//   empty asm so they can't sink into the branch, then pos-enc (~400 cyc of
//   v_sin VALU) runs while loads are in flight, then role-0 consumes.
//   Hides the HBM gather latency (dgrid ~134MB, L2-miss) that round-11
//   serialized inside the divergent role-0 block (~35% stall share).
// ---------------------------------------------------------------------------

typedef __attribute__((ext_vector_type(4))) float f4;
typedef long long llg;                                    // 8 x fp8
typedef __attribute__((ext_vector_type(2))) long long llg2;  // 16 x fp8 (4 VGPR)
typedef unsigned long long u64;

#define MFMA8 __builtin_amdgcn_mfma_f32_16x16x32_fp8_fp8
#define SCHED_FENCE() __builtin_amdgcn_sched_barrier(0)

__device__ __forceinline__ float bf2f(unsigned int u) {
    union { float f; unsigned int i; } v; v.i = u << 16; return v.f;
}
__device__ __forceinline__ unsigned int pkbf(float a, float b) {
    unsigned int r;
    asm("v_cvt_pk_bf16_f32 %0, %1, %2" : "=v"(r) : "v"(a), "v"(b));
    return r;
}
__device__ __forceinline__ float vfract(float a) {
    float d; asm("v_fract_f32 %0, %1" : "=v"(d) : "v"(a)); return d;
}
__device__ __forceinline__ float vsin(float a) {
    float d; asm("v_sin_f32 %0, %1" : "=v"(d) : "v"(a)); return d;
}
__device__ __forceinline__ float gv(const float* __restrict__ g, int i, int j, int k) {
    return g[(i * 256 + j) * 256 + k];
}
// feature permutation: slot k' -> original feature index (or -1 = zero pad)
__device__ __forceinline__ int featmap(int kp) {
    if (kp < 3) return kp;
    if (kp == 3) return -1;
    const int m = kp - 4, b = m / 6, r = m - 6 * b, d = r >> 1, c = r & 1;
    return 3 + 6 * b + 3 * c + d;
}
// hidden-layer K permutation: storage slot k -> producing-layer unit index,
// chosen so the producer's packed C dwords are directly the B-fragment.
__device__ __forceinline__ int hidperm(int k) {
    const int kt = k >> 5, q = (k >> 3) & 3, j = k & 7;
    return 32 * kt + ((j >> 2) << 4) + (q << 2) + (j & 3);
}
__device__ __forceinline__ llg mkllg(unsigned int lo, unsigned int hi) {
    return (llg)(((unsigned long long)lo) | (((unsigned long long)hi) << 32));
}
__device__ __forceinline__ unsigned int pack8(f4 acc) {
    int d = __builtin_amdgcn_cvt_pk_fp8_f32(fmaxf(acc[0], 0.f), fmaxf(acc[1], 0.f), 0, false);
    d     = __builtin_amdgcn_cvt_pk_fp8_f32(fmaxf(acc[2], 0.f), fmaxf(acc[3], 0.f), d, true);
    return (unsigned int)d;
}

// ---- d_ws layout ----
// bytes [0, 67584): fp8 weight fragments, PAIRED layout:
//   byte = region + ((nt*KTP + ktp)*64 + lane)*16 + half*8 + j,  kt = 2*ktp+half
//   L0@0 (K64, KTP=1), L1@8192 (K128, KTP=2), L2@24576, L3@40960 (K192, KTP=3),
//   out@65536 (K128, KTP=2, NT=1, wo*2^13)
// shorts from 131072 (byte 262144): bf16x4 data grid (16.7M voxels * 8 B)
#define WS_TOTAL 67584
#define SWZ_BLOCKS 264          // 264*256 == 67584 (one byte per thread)
#define DG_BLOCKS 8192          // 2^21 threads x 8 voxels
#define DG_OFF_SH 131072
#define WS_NEED (262144ull + 16777216ull * 8ull)
#define WO_SCALE 8192.0f
#define WO_INV   (1.0f / 8192.0f)
#define INV2PI 0.15915494309189535f

__global__ __launch_bounds__(256) void prep(
    const float* __restrict__ g,
    const float* __restrict__ w0, const float* __restrict__ w1,
    const float* __restrict__ w2, const float* __restrict__ w3,
    const float* __restrict__ wo,
    unsigned char* __restrict__ ws8, unsigned short* __restrict__ dg,
    int do_dgrid)
{
    const int bid = blockIdx.x;
    if (bid < SWZ_BLOCKS) {
        // ---------------- weight swizzle -> fp8 (paired layout) -----------
        int idx = bid * 256 + threadIdx.x;
        const float* src; int base, KTP, Kact, Nact, ld;
        if (idx < 8192)       { src = w0; base = 0;     KTP = 1; Kact = 64;  Nact = 128; ld = 128; }
        else if (idx < 24576) { src = w1; base = 8192;  KTP = 2; Kact = 128; Nact = 128; ld = 128; }
        else if (idx < 40960) { src = w2; base = 24576; KTP = 2; Kact = 128; Nact = 128; ld = 128; }
        else if (idx < 65536) { src = w3; base = 40960; KTP = 3; Kact = 192; Nact = 128; ld = 128; }
        else                  { src = wo; base = 65536; KTP = 2; Kact = 128; Nact = 3;   ld = 3;   }
        int local = idx - base;
        int j    = local & 7;
        int half = (local >> 3) & 1;
        int lane = (local >> 4) & 63;
        int c    = local >> 10;
        int ktp  = c % KTP, nt = c / KTP;
        int kt   = ktp * 2 + half;
        int k = kt * 32 + ((lane >> 4) << 3) + j;   // k = kt*32 + quad*8 + j
        int n = nt * 16 + (lane & 15);              // unit = nt*16 + (lane&15)
        float v = 0.0f;
        if (k < Kact && n < Nact) {
            int ko;
            if (base == 0) {
                ko = featmap(k);                     // L0: features
            } else if (base == 40960) {
                if (k >= 128) {                      // L3 tail: features
                    int f = featmap(k - 128);
                    ko = (f < 0) ? -1 : 128 + f;
                } else {
                    ko = hidperm(k);                 // L3 head: L2 units
                }
            } else {
                ko = hidperm(k);                     // L1/L2/out: hidden units
            }
            if (ko >= 0) v = src[ko * ld + n];
            if (base == 65536) v *= WO_SCALE;        // keep wo out of fp8 underflow
        }
        int p = __builtin_amdgcn_cvt_pk_fp8_f32(v, v, 0, false);
        ws8[idx] = (unsigned char)(p & 0xff);
    } else if (do_dgrid) {
        // ---------------- data grid build (8 voxels/thread) ----------------
        const int t  = (bid - SWZ_BLOCKS) * 256 + threadIdx.x;   // [0, 2^21)
        const int k0 = (t & 31) << 3;
        const int j  = (t >> 5) & 255;
        const int i  = t >> 13;
        const float* row = g + (i * 256 + j) * 256;
        const float* rxp = g + (min(i + 1, 255) * 256 + j) * 256;
        const float* rxm = g + (max(i - 1, 0)   * 256 + j) * 256;
        const float* ryp = g + (i * 256 + min(j + 1, 255)) * 256;
        const float* rym = g + (i * 256 + max(j - 1, 0))   * 256;
        float se[8], sxp[8], sxm[8], syp[8], sym[8];
        {
            f4 a = *(const f4*)(row + k0), b = *(const f4*)(row + k0 + 4);
            #pragma unroll
            for (int q = 0; q < 4; ++q) { se[q] = a[q]; se[q + 4] = b[q]; }
            a = *(const f4*)(rxp + k0); b = *(const f4*)(rxp + k0 + 4);
            #pragma unroll
            for (int q = 0; q < 4; ++q) { sxp[q] = a[q]; sxp[q + 4] = b[q]; }
            a = *(const f4*)(rxm + k0); b = *(const f4*)(rxm + k0 + 4);
            #pragma unroll
            for (int q = 0; q < 4; ++q) { sxm[q] = a[q]; sxm[q + 4] = b[q]; }
            a = *(const f4*)(ryp + k0); b = *(const f4*)(ryp + k0 + 4);
            #pragma unroll
            for (int q = 0; q < 4; ++q) { syp[q] = a[q]; syp[q + 4] = b[q]; }
            a = *(const f4*)(rym + k0); b = *(const f4*)(rym + k0 + 4);
            #pragma unroll
            for (int q = 0; q < 4; ++q) { sym[q] = a[q]; sym[q + 4] = b[q]; }
        }
        float zv[10];
        zv[0] = row[max(k0 - 1, 0)];
        #pragma unroll
        for (int q = 0; q < 8; ++q) zv[q + 1] = se[q];
        zv[9] = row[min(k0 + 8, 255)];
        unsigned int o[16];
        #pragma unroll
        for (int q = 0; q < 8; ++q) {
            o[q * 2 + 0] = pkbf(se[q], (sxp[q] - sxm[q]) * 63.75f);
            o[q * 2 + 1] = pkbf((syp[q] - sym[q]) * 63.75f, (zv[q + 2] - zv[q]) * 63.75f);
        }
        unsigned short* dst = dg + (size_t)(((i * 256 + j) * 256 + k0)) * 4;
        #pragma unroll
        for (int q = 0; q < 4; ++q)
            *(uint4*)(dst + q * 8) = *(const uint4*)(&o[q * 4]);
    }
}

// per-wave LDS (bytes): fbuf 32 rows x 88 B:
//   [0..63] fp8 features, [64..75] 3 fp32 c1..c3 stash.
#define FSTRIDE_B 88
#define WV_BYTES (32 * FSTRIDE_B)    // 2816

// Hidden layer (K=128): SRCP/DSTP are llg[2][4] pair arrays, pt-inner.
// SCHED_FENCE at each utp boundary bounds weight-fragment hoisting.
#define HIDDEN_LAYER(WSL, BIASP, SRCP, DSTP)                                    \
    do {                                                                        \
        _Pragma("unroll")                                                       \
        for (int utp = 0; utp < 4; ++utp) {                                     \
            const int utA = 2 * utp, utB = 2 * utp + 1;                         \
            llg2 wa0 = *(const llg2*)((WSL) + ((utA * 2 + 0) * 64 + lane) * 16);\
            llg2 wa1 = *(const llg2*)((WSL) + ((utA * 2 + 1) * 64 + lane) * 16);\
            llg2 wb0 = *(const llg2*)((WSL) + ((utB * 2 + 0) * 64 + lane) * 16);\
            llg2 wb1 = *(const llg2*)((WSL) + ((utB * 2 + 1) * 64 + lane) * 16);\
            const f4 biasA = *(const f4*)((BIASP) + utA * 16 + quad * 4);       \
            const f4 biasB = *(const f4*)((BIASP) + utB * 16 + quad * 4);       \
            _Pragma("unroll")                                                   \
            for (int pt = 0; pt < 2; ++pt) {                                    \
                f4 a0 = biasA, a1 = biasB;                                      \
                a0 = MFMA8(wa0[0], SRCP[pt][0], a0, 0, 0, 0);                   \
                a0 = MFMA8(wa0[1], SRCP[pt][1], a0, 0, 0, 0);                   \
                a0 = MFMA8(wa1[0], SRCP[pt][2], a0, 0, 0, 0);                   \
                a0 = MFMA8(wa1[1], SRCP[pt][3], a0, 0, 0, 0);                   \
                a1 = MFMA8(wb0[0], SRCP[pt][0], a1, 0, 0, 0);                   \
                a1 = MFMA8(wb0[1], SRCP[pt][1], a1, 0, 0, 0);                   \
                a1 = MFMA8(wb1[0], SRCP[pt][2], a1, 0, 0, 0);                   \
                a1 = MFMA8(wb1[1], SRCP[pt][3], a1, 0, 0, 0);                   \
                DSTP[pt][utp] = mkllg(pack8(a0), pack8(a1));                    \
            }                                                                   \
            SCHED_FENCE();                                                      \
        }                                                                       \
    } while (0)

template<bool FAST>
__global__ __launch_bounds__(256, 5) void voxmlp(
    const float* __restrict__ x, const float* __restrict__ grid,
    const unsigned char* __restrict__ ws8, const unsigned short* __restrict__ dg,
    const float* __restrict__ b0, const float* __restrict__ b1,
    const float* __restrict__ b2, const float* __restrict__ b3,
    const float* __restrict__ bo,
    float* __restrict__ out, int B)
{
    __shared__ unsigned char smem[WV_BYTES * 4];   // 11264 B

    const int lane = threadIdx.x & 63;
    const int wave = threadIdx.x >> 6;
    const int quad = lane >> 4;
    const int lm   = lane & 15;
    unsigned char* fbuf = smem + wave * WV_BYTES;

    const int pbase = blockIdx.x * 128 + wave * 32;

    // ================= Phase 1 ============================================
    const int p2   = lane & 31;
    const int role = lane >> 5;
    const int pid  = pbase + p2;

    const float px = x[pid * 3 + 0];
    const float py = x[pid * 3 + 1];
    const float pz = x[pid * 3 + 2];

    if (FAST) {
        // ---- all-lane trilinear setup + EARLY gather issue ----
        // role-1 lane l computes the same point as role-0 lane l-32 ->
        // identical addresses, duplicated loads hit the same cache lines.
        const float fx = (px + 1.0f) * 127.5f;
        const float fy = (py + 1.0f) * 127.5f;
        const float fz = (pz + 1.0f) * 127.5f;
        const float fx0 = floorf(fx), fy0 = floorf(fy), fz0 = floorf(fz);
        const float xd = fx - fx0, yd = fy - fy0, zd = fz - fz0;
        const int ix0 = min(max((int)fx0, 0), 255);
        const int iy0 = min(max((int)fy0, 0), 255);
        const int iz0 = min(max((int)fz0, 0), 255);
        const int ix1 = min(ix0 + 1, 255);
        const int iy1 = min(iy0 + 1, 255);
        const int iz1 = min(iz0 + 1, 255);

        const unsigned char* dgb = (const unsigned char*)dg;
        const unsigned int vbase = (unsigned int)((ix0 * 65536 + iy0 * 256 + iz0) << 3);
        const unsigned int ox = (unsigned int)((ix1 - ix0) << 19);
        const unsigned int oy = (unsigned int)((iy1 - iy0) << 11);
        const unsigned int oz = (unsigned int)((iz1 - iz0) << 3);

        u64 gl[8];
        #pragma unroll
        for (int c = 0; c < 8; ++c) {
            const unsigned int off = vbase + ((c & 4) ? ox : 0u)
                                           + ((c & 2) ? oy : 0u)
                                           + ((c & 1) ? oz : 0u);
            gl[c] = *(const u64*)(dgb + off);
        }
        // pin: force loads issued here, not sunk into the role-0 branch
        #pragma unroll
        for (int c = 0; c < 8; ++c)
            asm volatile("" : "+v"(gl[c]));

        if (role == 1) {
            // streamed pos-enc while gathers are in flight
            const float r0 = px * INV2PI, r1 = py * INV2PI, r2 = pz * INV2PI;
            unsigned char* fb = fbuf + p2 * FSTRIDE_B;
            auto slotv = [&](int n) -> float {
                if (n == 0) return px;
                if (n == 1) return py;
                if (n == 2) return pz;
                if (n == 3) return 0.0f;
                const int m = n - 4, b = m / 6, t = m % 6, ax = t >> 1, ph = t & 1;
                const float rr = (ax == 0) ? r0 : (ax == 1) ? r1 : r2;
                const float arg = rr * (float)(1 << b) + (ph ? 0.25f : 0.0f);
                return vsin(vfract(arg));
            };
            #pragma unroll
            for (int w = 0; w < 8; ++w) {
                int lo = __builtin_amdgcn_cvt_pk_fp8_f32(slotv(8 * w + 0), slotv(8 * w + 1), 0, false);
                lo     = __builtin_amdgcn_cvt_pk_fp8_f32(slotv(8 * w + 2), slotv(8 * w + 3), lo, true);
                int hi = __builtin_amdgcn_cvt_pk_fp8_f32(slotv(8 * w + 4), slotv(8 * w + 5), 0, false);
                hi     = __builtin_amdgcn_cvt_pk_fp8_f32(slotv(8 * w + 6), slotv(8 * w + 7), hi, true);
                uint2 pk; pk.x = (unsigned int)lo; pk.y = (unsigned int)hi;
                *(uint2*)(fb + w * 8) = pk;
            }
        } else {
            // consume gathers
            float ret0 = 0.f, c1 = 0.f, c2 = 0.f, c3 = 0.f;
            #pragma unroll
            for (int c = 0; c < 8; ++c) {
                const float wgt = ((c & 4) ? xd : 1.0f - xd) *
                                  ((c & 2) ? yd : 1.0f - yd) *
                                  ((c & 1) ? zd : 1.0f - zd);
                const unsigned int wx = (unsigned int)gl[c];
                const unsigned int wy = (unsigned int)(gl[c] >> 32);
                ret0 = fmaf(wgt, bf2f(wx & 0xffffu), ret0);
                c1   = fmaf(wgt, bf2f(wx >> 16),     c1);
                c2   = fmaf(wgt, bf2f(wy & 0xffffu), c2);
                c3   = fmaf(wgt, bf2f(wy >> 16),     c3);
            }
            out[pid] = ret0;
            out[B + pid * 3 + 0] = c1;
            out[B + pid * 3 + 1] = c2;
            out[B + pid * 3 + 2] = c3;
            float* cst = (float*)(fbuf + p2 * FSTRIDE_B + 64);
            cst[0] = c1; cst[1] = c2; cst[2] = c3;
        }
    } else {
        if (role == 0) {
            const float fx = (px + 1.0f) * 127.5f;
            const float fy = (py + 1.0f) * 127.5f;
            const float fz = (pz + 1.0f) * 127.5f;
            const float fx0 = floorf(fx), fy0 = floorf(fy), fz0 = floorf(fz);
            const float xd = fx - fx0, yd = fy - fy0, zd = fz - fz0;
            const int ix0 = min(max((int)fx0, 0), 255);
            const int iy0 = min(max((int)fy0, 0), 255);
            const int iz0 = min(max((int)fz0, 0), 255);
            const int ix1 = min(ix0 + 1, 255);
            const int iy1 = min(iy0 + 1, 255);
            const int iz1 = min(iz0 + 1, 255);
            float ret0 = 0.f, c1 = 0.f, c2 = 0.f, c3 = 0.f;
            #pragma unroll
            for (int c = 0; c < 8; ++c) {
                const int i = (c & 4) ? ix1 : ix0;
                const int j = (c & 2) ? iy1 : iy0;
                const int k = (c & 1) ? iz1 : iz0;
                const float wgt = ((c & 4) ? xd : 1.0f - xd) *
                                  ((c & 2) ? yd : 1.0f - yd) *
                                  ((c & 1) ? zd : 1.0f - zd);
                const float v  = gv(grid, i, j, k);
                const float gx = (gv(grid, min(i + 1, 255), j, k) - gv(grid, max(i - 1, 0), j, k)) * 63.75f;
                const float gy = (gv(grid, i, min(j + 1, 255), k) - gv(grid, i, max(j - 1, 0), k)) * 63.75f;
                const float gz = (gv(grid, i, j, min(k + 1, 255)) - gv(grid, i, j, max(k - 1, 0))) * 63.75f;
                ret0 = fmaf(wgt, v,  ret0);
                c1   = fmaf(wgt, gx, c1);
                c2   = fmaf(wgt, gy, c2);
                c3   = fmaf(wgt, gz, c3);
            }
            out[pid] = ret0;
            out[B + pid * 3 + 0] = c1;
            out[B + pid * 3 + 1] = c2;
            out[B + pid * 3 + 2] = c3;
            float* cst = (float*)(fbuf + p2 * FSTRIDE_B + 64);
            cst[0] = c1; cst[1] = c2; cst[2] = c3;
        } else {
            const float r0 = px * INV2PI, r1 = py * INV2PI, r2 = pz * INV2PI;
            unsigned char* fb = fbuf + p2 * FSTRIDE_B;
            auto slotv = [&](int n) -> float {
                if (n == 0) return px;
                if (n == 1) return py;
                if (n == 2) return pz;
                if (n == 3) return 0.0f;
                const int m = n - 4, b = m / 6, t = m % 6, ax = t >> 1, ph = t & 1;
                const float rr = (ax == 0) ? r0 : (ax == 1) ? r1 : r2;
                const float arg = rr * (float)(1 << b) + (ph ? 0.25f : 0.0f);
                return vsin(vfract(arg));
            };
            #pragma unroll
            for (int w = 0; w < 8; ++w) {
                int lo = __builtin_amdgcn_cvt_pk_fp8_f32(slotv(8 * w + 0), slotv(8 * w + 1), 0, false);
                lo     = __builtin_amdgcn_cvt_pk_fp8_f32(slotv(8 * w + 2), slotv(8 * w + 3), lo, true);
                int hi = __builtin_amdgcn_cvt_pk_fp8_f32(slotv(8 * w + 4), slotv(8 * w + 5), 0, false);
                hi     = __builtin_amdgcn_cvt_pk_fp8_f32(slotv(8 * w + 6), slotv(8 * w + 7), hi, true);
                uint2 pk; pk.x = (unsigned int)lo; pk.y = (unsigned int)hi;
                *(uint2*)(fb + w * 8) = pk;
            }
        }
    }
    __builtin_amdgcn_s_barrier();   // phase-align waves (weight L1 reuse)

    // ================= MLP via fp8 MFMA, activations as llg pairs =========
    const int frow0 = lm * FSTRIDE_B + quad * 8;

    llg actA[2][4];   // L0 out, later L2 out
    llg actB[2][4];   // L1 out, later L3 out
    llg ffp[2][2];    // feature fragments (used by L0 and L3)

    #pragma unroll
    for (int pt = 0; pt < 2; ++pt)
        #pragma unroll
        for (int kt = 0; kt < 2; ++kt)
            ffp[pt][kt] = *(const llg*)(fbuf + pt * 16 * FSTRIDE_B + frow0 + kt * 32);

    // ---- L0: features (K=64, KTP=1) -> actA ----
    #pragma unroll
    for (int utp = 0; utp < 4; ++utp) {
        const int utA = 2 * utp, utB = 2 * utp + 1;
        llg2 wA = *(const llg2*)(ws8 + (utA * 64 + lane) * 16);
        llg2 wB = *(const llg2*)(ws8 + (utB * 64 + lane) * 16);
        const f4 biasA = *(const f4*)(b0 + utA * 16 + quad * 4);
        const f4 biasB = *(const f4*)(b0 + utB * 16 + quad * 4);
        #pragma unroll
        for (int pt = 0; pt < 2; ++pt) {
            f4 a0 = biasA, a1 = biasB;
            a0 = MFMA8(wA[0], ffp[pt][0], a0, 0, 0, 0);
            a0 = MFMA8(wA[1], ffp[pt][1], a0, 0, 0, 0);
            a1 = MFMA8(wB[0], ffp[pt][0], a1, 0, 0, 0);
            a1 = MFMA8(wB[1], ffp[pt][1], a1, 0, 0, 0);
            actA[pt][utp] = mkllg(pack8(a0), pack8(a1));
        }
        SCHED_FENCE();
    }

    // ---- L1, L2 (K=128, KTP=2) ----
    HIDDEN_LAYER(ws8 + 8192,  b1, actA, actB);
    HIDDEN_LAYER(ws8 + 24576, b2, actB, actA);

    // ---- L3: concat(actA K=128, features K=64) -> actB  (KTP=3) ----
    #pragma unroll
    for (int utp = 0; utp < 4; ++utp) {
        const int utA = 2 * utp, utB = 2 * utp + 1;
        llg2 ha0 = *(const llg2*)(ws8 + 40960 + ((utA * 3 + 0) * 64 + lane) * 16);
        llg2 ha1 = *(const llg2*)(ws8 + 40960 + ((utA * 3 + 1) * 64 + lane) * 16);
        llg2 ha2 = *(const llg2*)(ws8 + 40960 + ((utA * 3 + 2) * 64 + lane) * 16);
        llg2 hb0 = *(const llg2*)(ws8 + 40960 + ((utB * 3 + 0) * 64 + lane) * 16);
        llg2 hb1 = *(const llg2*)(ws8 + 40960 + ((utB * 3 + 1) * 64 + lane) * 16);
        llg2 hb2 = *(const llg2*)(ws8 + 40960 + ((utB * 3 + 2) * 64 + lane) * 16);
        const f4 biasA = *(const f4*)(b3 + utA * 16 + quad * 4);
        const f4 biasB = *(const f4*)(b3 + utB * 16 + quad * 4);
        #pragma unroll
        for (int pt = 0; pt < 2; ++pt) {
            f4 a0 = biasA, a1 = biasB;
            a0 = MFMA8(ha0[0], actA[pt][0], a0, 0, 0, 0);
            a0 = MFMA8(ha0[1], actA[pt][1], a0, 0, 0, 0);
            a0 = MFMA8(ha1[0], actA[pt][2], a0, 0, 0, 0);
            a0 = MFMA8(ha1[1], actA[pt][3], a0, 0, 0, 0);
            a0 = MFMA8(ha2[0], ffp[pt][0],  a0, 0, 0, 0);
            a0 = MFMA8(ha2[1], ffp[pt][1],  a0, 0, 0, 0);
            a1 = MFMA8(hb0[0], actA[pt][0], a1, 0, 0, 0);
            a1 = MFMA8(hb0[1], actA[pt][1], a1, 0, 0, 0);
            a1 = MFMA8(hb1[0], actA[pt][2], a1, 0, 0, 0);
            a1 = MFMA8(hb1[1], actA[pt][3], a1, 0, 0, 0);
            a1 = MFMA8(hb2[0], ffp[pt][0],  a1, 0, 0, 0);
            a1 = MFMA8(hb2[1], ffp[pt][1],  a1, 0, 0, 0);
            actB[pt][utp] = mkllg(pack8(a0), pack8(a1));
        }
        SCHED_FENCE();
    }

    // ---- output layer (K=128, KTP=2, N=3, wo scaled 2^13) + epilogue ----
    const llg2 o0 = *(const llg2*)(ws8 + 65536 + (lane * 16));
    const llg2 o1 = *(const llg2*)(ws8 + 65536 + ((64 + lane) * 16));

    const float bo0 = bo[0], bo1 = bo[1], bo2 = bo[2];
    #pragma unroll
    for (int pt = 0; pt < 2; ++pt) {
        f4 acc = {0.f, 0.f, 0.f, 0.f};
        acc = MFMA8(o0[0], actB[pt][0], acc, 0, 0, 0);
        acc = MFMA8(o0[1], actB[pt][1], acc, 0, 0, 0);
        acc = MFMA8(o1[0], actB[pt][2], acc, 0, 0, 0);
        acc = MFMA8(o1[1], actB[pt][3], acc, 0, 0, 0);

        const int pp = pt * 16 + lm;
        const float* cst = (const float*)(fbuf + pp * FSTRIDE_B + 64);
        const float g1 = cst[0], g2 = cst[1], g3 = cst[2];
        const float r0 = acc[0] * WO_INV + bo0;
        const float r1 = acc[1] * WO_INV + bo1;
        const float r2 = acc[2] * WO_INV + bo2;
        const float theta = sqrtf(fmaf(r0, r0, fmaf(r1, r1, r2 * r2)) + 1e-12f);
        const float it = __builtin_amdgcn_rcpf(theta);
        const float e0 = r0 * it, e1 = r1 * it, e2 = r2 * it;
        const float a = sqrtf(fmaf(g1, g1, fmaf(g2, g2, g3 * g3)) + 1e-12f);
        const float ia = __builtin_amdgcn_rcpf(a);
        const float v0 = g1 * ia, v1 = g2 * ia, v2 = g3 * ia;
        const float rv = theta * INV2PI;
        const float st = vsin(vfract(rv));
        const float ct = vsin(vfract(rv + 0.25f));
        const float cx = e1 * v2 - e2 * v1;
        const float cy = e2 * v0 - e0 * v2;
        const float cz = e0 * v1 - e1 * v0;
        const float om = (1.0f - ct) * (e0 * v0 + e1 * v1 + e2 * v2);
        if (quad == 0) {
            const int pid2 = pbase + pp;
            out[4 * B + pid2 * 3 + 0] = a * (ct * v0 + st * cx + om * e0);
            out[4 * B + pid2 * 3 + 1] = a * (ct * v1 + st * cy + om * e1);
            out[4 * B + pid2 * 3 + 2] = a * (ct * v2 + st * cz + om * e2);
        }
    }
}

extern "C" void kernel_launch(void* const* d_in, const int* in_sizes, int n_in,
                              void* d_out, int out_size, void* d_ws, size_t ws_size,
                              hipStream_t stream)
{
    const float* x    = (const float*)d_in[0];
    const float* grid = (const float*)d_in[1];
    const float* w0   = (const float*)d_in[2];
    const float* b0   = (const float*)d_in[3];
    const float* w1   = (const float*)d_in[4];
    const float* b1   = (const float*)d_in[5];
    const float* w2   = (const float*)d_in[6];
    const float* b2   = (const float*)d_in[7];
    const float* w3   = (const float*)d_in[8];
    const float* b3   = (const float*)d_in[9];
    const float* wo   = (const float*)d_in[10];
    const float* bo   = (const float*)d_in[11];
    float* out = (float*)d_out;
    unsigned char* ws8 = (unsigned char*)d_ws;
    unsigned short* dg = (unsigned short*)d_ws + DG_OFF_SH;

    const int B = in_sizes[0] / 3;        // 1,048,576
    const int fast = (ws_size >= WS_NEED) ? 1 : 0;
    const int nprep = fast ? (SWZ_BLOCKS + DG_BLOCKS) : SWZ_BLOCKS;
    prep<<<nprep, 256, 0, stream>>>(grid, w0, w1, w2, w3, wo, ws8, dg, fast);
    if (fast)
        voxmlp<true><<<B / 128, 256, 0, stream>>>(x, grid, ws8, dg, b0, b1, b2, b3, bo, out, B);
    else
        voxmlp<false><<<B / 128, 256, 0, stream>>>(x, grid, ws8, dg, b0, b1, b2, b3, bo, out, B);
}